// Round 18
// baseline (716.781 us; speedup 1.0000x reference)
//
#include <hip/hip_runtime.h>

#define NTOT 4096
#define NBATCH 4
#define KNN 20
#define JSPLIT 8
#define KMRG 24
#define CSLOTM 512  // MFMA-path candidate slots per point (64 lists x 8)

constexpr float NEG_INF = -3.0e38f;

typedef __attribute__((ext_vector_type(8))) short bf16x8;
typedef __attribute__((ext_vector_type(4))) float f32x4;

__device__ __forceinline__ unsigned pk(float f, int j) {
  unsigned u = __float_as_uint(f);
  u = (u & 0x80000000u) ? ~u : (u | 0x80000000u);
  return (u & 0xFFFFF000u) | (unsigned)j;
}

__device__ __forceinline__ void pins8(unsigned u, unsigned (&tv)[8]) {
  if (u > tv[0]) {
    tv[0] = u;
#pragma unroll
    for (int x = 1; x < 8; x++) {
      unsigned mn = min(tv[0], tv[x]);
      unsigned mx = max(tv[0], tv[x]);
      tv[0] = mn;
      tv[x] = mx;
    }
  }
}

// split-bf16: x = hi + lo (round-to-nearest-even at each step)
__device__ __forceinline__ void sbf16(float x, ushort& h16, ushort& l16) {
  unsigned u = __float_as_uint(x);
  unsigned h = (u + 0x7FFFu + ((u >> 16) & 1u)) >> 16;
  float hf = __uint_as_float(h << 16);
  float r = x - hf;
  unsigned v = __float_as_uint(r);
  unsigned l = (v + 0x7FFFu + ((v >> 16) & 1u)) >> 16;
  h16 = (ushort)h;
  l16 = (ushort)l;
}

// async global->LDS 16B copy (lane i writes lds + i*16)
__device__ __forceinline__ void gll16(const void* g, void* l) {
  __builtin_amdgcn_global_load_lds(
      (const __attribute__((address_space(1))) unsigned int*)g,
      (__attribute__((address_space(3))) unsigned int*)l, 16, 0, 0);
}

// ---------------- prep: fold BN scale into weights (fp32 + split-bf16) -----
__global__ void prep_w(const float* __restrict__ W, const float* __restrict__ gg,
                       const float* __restrict__ bb, const float* __restrict__ mm,
                       const float* __restrict__ vv, float* __restrict__ Wc,
                       float* __restrict__ bias, ushort* __restrict__ Wch,
                       ushort* __restrict__ Wcl, int O, int C) {
  int t = blockIdx.x * 256 + threadIdx.x;
  if (t >= 2 * O * C) return;
  int o2 = t / C, c = t - o2 * C;
  int o = (o2 < O) ? o2 : o2 - O;
  float s = gg[o] * rsqrtf(vv[o] + 1e-5f);
  float w = (o2 < O) ? W[o * 2 * C + c] * s
                     : (W[o * 2 * C + C + c] - W[o * 2 * C + c]) * s;
  Wc[o2 * C + c] = w;
  ushort h16, l16;
  sbf16(w, h16, l16);
  Wch[o2 * C + c] = h16;
  Wcl[o2 * C + c] = l16;
  if (o2 >= O && c == 0) bias[o] = bb[o] - mm[o] * s;
}

// layer-1: (B,N,3) fp32 -> (B,N,32) split-bf16, dims 3..31 zero
__global__ void cvt3_k(const float* __restrict__ f, ushort* __restrict__ hi,
                       ushort* __restrict__ lo) {
  int p = blockIdx.x * 256 + threadIdx.x;  // over NBATCH*NTOT*32
  int pt = p >> 5, dim = p & 31;
  float x = (dim < 3) ? f[pt * 3 + dim] : 0.f;
  ushort h16, l16;
  sbf16(x, h16, l16);
  hi[p] = h16;
  lo[p] = l16;
}

__global__ void sqh3_k(const float* __restrict__ f, float* __restrict__ sqh) {
  int p = blockIdx.x * 256 + threadIdx.x;  // NBATCH*NTOT
  float a = f[(size_t)p * 3 + 0];
  float b2 = f[(size_t)p * 3 + 1];
  float c = f[(size_t)p * 3 + 2];
  sqh[p] = 0.5f * (a * a + b2 * b2 + c * c);
}

// ---------------- KNN stage 1: pipelined gll + swapped MFMA, js-pair -------
// (r12/r14-verified 512-thread form; unchanged)
template <int C>
__global__ __launch_bounds__(512, 4) void knn_m(const ushort* __restrict__ Xhi,
                                                const ushort* __restrict__ Xlo,
                                                const float* __restrict__ sqh,
                                                unsigned* __restrict__ cval) {
  constexpr int NK = C / 32;
  constexpr int NJT = NTOT / (128 * JSPLIT);  // 4
  constexpr int NSQ = 2 * NJT;                // 8 seq j-tiles (js pair)
  __shared__ __align__(16) char smem[69632];  // 2x32KB bufs + sqB 4KB
  float* sqB = (float*)(smem + 65536);

  int tid = threadIdx.x;
  int raw = blockIdx.x;  // 512 blocks: [itHi(4)|jsp(2)|it0(1)|b(2)]
  int b = raw & 3;
  int jsp = (raw >> 3) & 3;
  int it = (((raw >> 5) & 15) << 1) | ((raw >> 2) & 1);
  int i0 = it * 128;
  int jpbase = jsp * 1024;
  const ushort* xh = Xhi + (size_t)b * NTOT * C;
  const ushort* xl = Xlo + (size_t)b * NTOT * C;

  int l = tid & 63, wid = tid >> 6;  // wid 0..7
  int wi = wid & 3, wj = wid >> 2;
  int n = l & 15, quad = l >> 4;
  int xr16 = (n & 7) << 4;  // read-side XOR ((row&7)<<4; row&7 == n&7)

  // gll source decode: stored chunk c = (R*4+q) ^ (R&7); invert for c = lane
  int t0 = l & 1, t1 = (l >> 1) & 1, t2 = (l >> 2) & 1, t3 = (l >> 3) & 1,
      t4 = (l >> 4) & 1, t5 = (l >> 5) & 1;
  int Rl = (t2 ^ t4) | (t3 << 1) | (t4 << 2) | (t5 << 3);
  int ql = (t0 ^ t2 ^ t4) | ((t1 ^ t3) << 1);

  if (tid < 256) {
    float4 s4 = *(const float4*)&sqh[b * NTOT + jpbase + tid * 4];
    *(float4*)&sqB[tid * 4] = s4;
  }
  __syncthreads();  // publish sqB + drain its load before counted-vmcnt phase

  unsigned tv[2][8];
#pragma unroll
  for (int ti = 0; ti < 2; ti++)
#pragma unroll
    for (int x = 0; x < 8; x++) tv[ti][x] = 0u;

  // 4 glls per wave per chunk: {Ah,Al,Bh,Bl} x 1 band of 16 rows (band=wid)
  auto issue = [&](int sn, int kcn, char* buf) {
    int j0n = jpbase + sn * 128;
    int R = Rl + wid * 16;
    size_t gA = (size_t)(i0 + R) * C + kcn + ql * 8;
    size_t gB = (size_t)(j0n + R) * C + kcn + ql * 8;
    char* ld = buf + wid * 1024;
    gll16(xh + gA, ld);            // Ah
    gll16(xl + gA, ld + 8192);     // Al
    gll16(xh + gB, ld + 16384);    // Bh
    gll16(xl + gB, ld + 24576);    // Bl
  };

  issue(0, 0, smem);  // prologue: chunk 0 -> buf0

  int g = 0;
  for (int s = 0; s < NSQ; s++) {
    int j0 = jpbase + s * 128;

    f32x4 acc[4][2];  // [tj][ti]: j in regs, i = lane col
#pragma unroll
    for (int tj = 0; tj < 4; tj++)
#pragma unroll
      for (int ti = 0; ti < 2; ti++) acc[tj][ti] = (f32x4)(0.f);

    for (int kc = 0; kc < NK; kc++) {
      __builtin_amdgcn_s_barrier();  // (A) all waves done reading target buf
      int nsn = (kc + 1 < NK) ? s : ((s + 1 == NSQ) ? 0 : s + 1);
      int nkc = (kc + 1 < NK) ? (kc + 1) * 32 : 0;
      issue(nsn, nkc, smem + ((g + 1) & 1) * 32768);
      asm volatile("s_waitcnt vmcnt(4)" ::: "memory");  // chunk g landed
      __builtin_amdgcn_s_barrier();                     // (C) data visible
      const char* bc = smem + (g & 1) * 32768;

      bf16x8 ah[2], al_[2];
#pragma unroll
      for (int ti = 0; ti < 2; ti++) {
        int row = wi * 32 + ti * 16 + n;
        int off = (row * 64 + quad * 16) ^ xr16;
        ah[ti] = *(const bf16x8*)(bc + off);
        al_[ti] = *(const bf16x8*)(bc + 8192 + off);
      }
#pragma unroll
      for (int tj = 0; tj < 4; tj++) {
        int row = wj * 64 + tj * 16 + n;
        int off = (row * 64 + quad * 16) ^ xr16;
        bf16x8 bh = *(const bf16x8*)(bc + 16384 + off);
        bf16x8 bl = *(const bf16x8*)(bc + 24576 + off);
#pragma unroll
        for (int ti = 0; ti < 2; ti++) {
          acc[tj][ti] = __builtin_amdgcn_mfma_f32_16x16x32_bf16(bh, ah[ti], acc[tj][ti], 0, 0, 0);
          acc[tj][ti] = __builtin_amdgcn_mfma_f32_16x16x32_bf16(bh, al_[ti], acc[tj][ti], 0, 0, 0);
          acc[tj][ti] = __builtin_amdgcn_mfma_f32_16x16x32_bf16(bl, ah[ti], acc[tj][ti], 0, 0, 0);
        }
      }
      g++;
    }

    float4 sq4[4];
#pragma unroll
    for (int tj = 0; tj < 4; tj++)
      sq4[tj] = *(const float4*)&sqB[s * 128 + wj * 64 + tj * 16 + quad * 4];
#pragma unroll
    for (int ti = 0; ti < 2; ti++) {
#pragma unroll
      for (int tj = 0; tj < 4; tj++) {
        float v0 = acc[tj][ti][0] - sq4[tj].x;
        float v1 = acc[tj][ti][1] - sq4[tj].y;
        float v2 = acc[tj][ti][2] - sq4[tj].z;
        float v3 = acc[tj][ti][3] - sq4[tj].w;
        float m4 = fmaxf(fmaxf(v0, v1), fmaxf(v2, v3));
        if (pk(m4, 0xFFF) > tv[ti][0]) {
          int jb = j0 + wj * 64 + tj * 16 + quad * 4;
          pins8(pk(v0, jb + 0), tv[ti]);
          pins8(pk(v1, jb + 1), tv[ti]);
          pins8(pk(v2, jb + 2), tv[ti]);
          pins8(pk(v3, jb + 3), tv[ti]);
        }
      }
    }

    // js-phase boundary: write out lists for this js, reset tv
    if (s == NJT - 1 || s == NSQ - 1) {
      int js = jsp * 2 + ((s == NSQ - 1) ? 1 : 0);
#pragma unroll
      for (int ti = 0; ti < 2; ti++) {
        int p = b * NTOT + i0 + wi * 32 + ti * 16 + n;
        unsigned* dst = cval + (size_t)p * CSLOTM + js * 64 + wj * 32 + quad * 8;
        uint4 o0, o1;
        o0.x = tv[ti][0]; o0.y = tv[ti][1]; o0.z = tv[ti][2]; o0.w = tv[ti][3];
        o1.x = tv[ti][4]; o1.y = tv[ti][5]; o1.z = tv[ti][6]; o1.w = tv[ti][7];
        *(uint4*)&dst[0] = o0;
        *(uint4*)&dst[4] = o1;
#pragma unroll
        for (int x = 0; x < 8; x++) tv[ti][x] = 0u;
      }
    }
  }
}

// ---------------- wave-per-2-points merge + refine + bitonic top-20 --------
// (r13/r14-verified) ILP-2: each wave processes TWO points with the pt loop
// INSIDE each stage so the two independent shuffle chains interleave.
template <int C, int NC>
__global__ __launch_bounds__(256) void kref_w(const float* __restrict__ feat,
                                              const unsigned* __restrict__ cval,
                                              int* __restrict__ outidx) {
  int tid = threadIdx.x;
  int lane = tid & 63;
  int pbase = blockIdx.x * 8 + (tid >> 6) * 2;

  unsigned c[2][8];
  int bq[2], iq[2];
#pragma unroll
  for (int pt = 0; pt < 2; pt++) {
    int p = pbase + pt;
    bq[pt] = p >> 12;
    iq[pt] = p & (NTOT - 1);
    uint4 aa = *(const uint4*)&cval[(size_t)p * NC + lane * 8];
    uint4 bb2 = *(const uint4*)&cval[(size_t)p * NC + lane * 8 + 4];
    c[pt][0] = aa.x; c[pt][1] = aa.y; c[pt][2] = aa.z; c[pt][3] = aa.w;
    c[pt][4] = bb2.x; c[pt][5] = bb2.y; c[pt][6] = bb2.z; c[pt][7] = bb2.w;
  }

  // sort each lane-list descending: optimal 19-CE network (c[0] = max)
#define CE(a, bq2)                          \
  {                                         \
    unsigned mx = max(c[pt][a], c[pt][bq2]); \
    unsigned mn = min(c[pt][a], c[pt][bq2]); \
    c[pt][a] = mx;                          \
    c[pt][bq2] = mn;                        \
  }
#pragma unroll
  for (int pt = 0; pt < 2; pt++) {
    CE(0, 1) CE(2, 3) CE(4, 5) CE(6, 7)
    CE(0, 2) CE(1, 3) CE(4, 6) CE(5, 7)
    CE(1, 2) CE(5, 6) CE(0, 4) CE(3, 7)
    CE(1, 5) CE(2, 6)
    CE(1, 4) CE(3, 6)
    CE(2, 4) CE(3, 5)
    CE(3, 4)
  }
#undef CE

  int myj[2] = {-1, -1};
#pragma unroll
  for (int t = 0; t < KMRG; t++) {
#pragma unroll
    for (int pt = 0; pt < 2; pt++) {
      unsigned m = c[pt][0];
#pragma unroll
      for (int s = 1; s < 64; s <<= 1)
        m = max(m, (unsigned)__shfl_xor((int)m, s));
      if (lane == t) myj[pt] = (int)(m & 0xFFFu);
      bool mine = (c[pt][0] == m);
      c[pt][0] = mine ? c[pt][1] : c[pt][0];
      c[pt][1] = mine ? c[pt][2] : c[pt][1];
      c[pt][2] = mine ? c[pt][3] : c[pt][2];
      c[pt][3] = mine ? c[pt][4] : c[pt][3];
      c[pt][4] = mine ? c[pt][5] : c[pt][4];
      c[pt][5] = mine ? c[pt][6] : c[pt][5];
      c[pt][6] = mine ? c[pt][7] : c[pt][6];
      c[pt][7] = mine ? 0u : c[pt][7];
    }
  }

  float myval[2] = {NEG_INF, NEG_INF};
  if constexpr (C == 3) {
#pragma unroll
    for (int pt = 0; pt < 2; pt++) {
      const float* fb = feat + (size_t)bq[pt] * NTOT * 3;
      if (lane < KMRG) {
        float x0 = fb[(size_t)iq[pt] * 3 + 0];
        float x1 = fb[(size_t)iq[pt] * 3 + 1];
        float x2 = fb[(size_t)iq[pt] * 3 + 2];
        float y0 = fb[(size_t)myj[pt] * 3 + 0];
        float y1 = fb[(size_t)myj[pt] * 3 + 1];
        float y2 = fb[(size_t)myj[pt] * 3 + 2];
        float d0 = x0 - y0, d1 = x1 - y1, d2 = x2 - y2;
        myval[pt] = -(d0 * d0 + d1 * d1 + d2 * d2);
      }
    }
  } else {
    constexpr int SL = C / 8;  // dims per lane within 8-lane group (8 or 16)
    int m8 = lane & 7;
    float4 xs[2][SL / 4];
#pragma unroll
    for (int pt = 0; pt < 2; pt++)
#pragma unroll
      for (int q4 = 0; q4 < SL / 4; q4++)
        xs[pt][q4] = *(const float4*)&feat[((size_t)bq[pt] * NTOT + iq[pt]) * C +
                                           m8 * SL + q4 * 4];
#pragma unroll
    for (int ps = 0; ps < KMRG / 8; ps++) {
      int src = ps * 8 + (lane >> 3);
#pragma unroll
      for (int pt = 0; pt < 2; pt++) {
        int j = __shfl(myj[pt], src);
        float d = 0.f;
#pragma unroll
        for (int q4 = 0; q4 < SL / 4; q4++) {
          float4 yv = *(const float4*)&feat[((size_t)bq[pt] * NTOT + j) * C +
                                            m8 * SL + q4 * 4];
          float dx = xs[pt][q4].x - yv.x;
          float dy = xs[pt][q4].y - yv.y;
          float dz = xs[pt][q4].z - yv.z;
          float dw = xs[pt][q4].w - yv.w;
          d += dx * dx + dy * dy + dz * dz + dw * dw;
        }
#pragma unroll
        for (int s = 1; s < 8; s <<= 1) d += __shfl_xor(d, s);
        float sd = __shfl(d, (lane & 7) << 3);
        bool upd = ((lane >> 3) == ps);
        myval[pt] = upd ? -sd : myval[pt];
      }
    }
  }

  // bitonic sort, 64 lanes, descending (lane 0 = best); ties -> smaller idx
#pragma unroll
  for (int k = 2; k <= 64; k <<= 1) {
#pragma unroll
    for (int j2 = k >> 1; j2 > 0; j2 >>= 1) {
#pragma unroll
      for (int pt = 0; pt < 2; pt++) {
        float ov = __shfl_xor(myval[pt], j2);
        int oj = __shfl_xor(myj[pt], j2);
        bool ogt = (ov > myval[pt]) || (ov == myval[pt] && oj < myj[pt]);
        bool lower = ((lane & j2) == 0);
        bool desc = ((lane & k) == 0);
        bool take = (desc == (lower == ogt));
        myval[pt] = take ? ov : myval[pt];
        myj[pt] = take ? oj : myj[pt];
      }
    }
  }

#pragma unroll
  for (int pt = 0; pt < 2; pt++)
    if (lane < KNN) outidx[(size_t)(pbase + pt) * KNN + lane] = myj[pt];
}

// ---------------- 128x128 fp32 GEMM (layers 2-3): Y = A * Wc^T -------------
// (r14-verified; fp32 activations are load-bearing for downstream KNN tie
// stability — do NOT replace with split-bf16 here.)
__global__ __launch_bounds__(256) void gemm128(const float* __restrict__ A,
                                               const float* __restrict__ Wc,
                                               const float* __restrict__ bias,
                                               float* __restrict__ Y, int K, int N2,
                                               int O) {
  constexpr int P = 140;
  __shared__ float As[16 * P];
  __shared__ float Bs[16 * P];
  int tid = threadIdx.x;
  int n0 = blockIdx.x * 128;
  int m0 = blockIdx.y * 128;
  int tx = tid & 15, ty = tid >> 4;
  int aoff = (ty * 8) + (((ty * 8) >> 5) << 2);
  int boff = (tx * 8) + (((tx * 8) >> 5) << 2);
  float acc[8][8];
#pragma unroll
  for (int ii = 0; ii < 8; ii++)
#pragma unroll
    for (int jj = 0; jj < 8; jj++) acc[ii][jj] = 0.f;

  for (int kc = 0; kc < K; kc += 16) {
    __syncthreads();
#pragma unroll
    for (int l = 0; l < 2; l++) {
      int e = tid + 256 * l;
      int rr = e >> 2, c4 = e & 3;
      int sc = rr + ((rr >> 5) << 2);
      float4 va = *(const float4*)&A[(size_t)(m0 + rr) * K + kc + c4 * 4];
      As[(c4 * 4 + 0) * P + sc] = va.x;
      As[(c4 * 4 + 1) * P + sc] = va.y;
      As[(c4 * 4 + 2) * P + sc] = va.z;
      As[(c4 * 4 + 3) * P + sc] = va.w;
      float4 vb = *(const float4*)&Wc[(size_t)(n0 + rr) * K + kc + c4 * 4];
      Bs[(c4 * 4 + 0) * P + sc] = vb.x;
      Bs[(c4 * 4 + 1) * P + sc] = vb.y;
      Bs[(c4 * 4 + 2) * P + sc] = vb.z;
      Bs[(c4 * 4 + 3) * P + sc] = vb.w;
    }
    __syncthreads();
#pragma unroll 8
    for (int k = 0; k < 16; k++) {
      float4 a0 = *(const float4*)&As[k * P + aoff];
      float4 a1 = *(const float4*)&As[k * P + aoff + 4];
      float4 b0 = *(const float4*)&Bs[k * P + boff];
      float4 b1 = *(const float4*)&Bs[k * P + boff + 4];
      float av[8] = {a0.x, a0.y, a0.z, a0.w, a1.x, a1.y, a1.z, a1.w};
      float bv[8] = {b0.x, b0.y, b0.z, b0.w, b1.x, b1.y, b1.z, b1.w};
#pragma unroll
      for (int ii = 0; ii < 8; ii++)
#pragma unroll
        for (int jj = 0; jj < 8; jj++)
          acc[ii][jj] = fmaf(av[ii], bv[jj], acc[ii][jj]);
    }
  }

  int col0 = n0 + tx * 8;
  float bv[8];
#pragma unroll
  for (int jj = 0; jj < 8; jj++) {
    int col = col0 + jj;
    bv[jj] = (col >= O) ? bias[col - O] : 0.f;
  }
#pragma unroll
  for (int ii = 0; ii < 8; ii++) {
    int row = m0 + ty * 8 + ii;
    float4 o0, o1;
    o0.x = acc[ii][0] + bv[0];
    o0.y = acc[ii][1] + bv[1];
    o0.z = acc[ii][2] + bv[2];
    o0.w = acc[ii][3] + bv[3];
    o1.x = acc[ii][4] + bv[4];
    o1.y = acc[ii][5] + bv[5];
    o1.z = acc[ii][6] + bv[6];
    o1.w = acc[ii][7] + bv[7];
    *(float4*)&Y[(size_t)row * N2 + col0] = o0;
    *(float4*)&Y[(size_t)row * N2 + col0 + 4] = o1;
  }
}

// ---------------- split-bf16 MFMA GEMM (FINAL layer only): Y = X * Wc^T ----
// r17's serial-MFMA-chain bottleneck fixed with ns-interleaving (ILP-4):
// 4 independent accumulators, dependency distance >= 9 MFMAs — covers MFMA
// latency even at 1 wave/SIMD. Per-(ns,kc) arithmetic order unchanged.
template <int C, int N2>
__global__ __launch_bounds__(256) void gemm_m(const ushort* __restrict__ Xh,
                                              const ushort* __restrict__ Xl,
                                              const ushort* __restrict__ Wh,
                                              const ushort* __restrict__ Wl,
                                              const float* __restrict__ bias,
                                              float* __restrict__ Y) {
  constexpr int NK = C / 32;
  constexpr int O = N2 / 2;
  int tid = threadIdx.x;
  int l = tid & 63, wid = tid >> 6;
  int n = l & 15, quad = l >> 4;
  int m0 = blockIdx.x * 64 + wid * 16;  // this wave's 16 m-rows

  // X panel: fragment rows indexed by lane n (row m0+n), k-slice by quad
  bf16x8 xh[NK], xl_[NK];
#pragma unroll
  for (int kc = 0; kc < NK; kc++) {
    size_t gx = (size_t)(m0 + n) * C + kc * 32 + quad * 8;
    xh[kc] = *(const bf16x8*)&Xh[gx];
    xl_[kc] = *(const bf16x8*)&Xl[gx];
  }

  for (int ng = 0; ng < N2 / 16; ng += 4) {
    f32x4 acc[4];
#pragma unroll
    for (int u = 0; u < 4; u++) acc[u] = (f32x4)(0.f);
#pragma unroll
    for (int kc = 0; kc < NK; kc++) {
#pragma unroll
      for (int u = 0; u < 4; u++) {
        size_t gw = (size_t)((ng + u) * 16 + n) * C + kc * 32 + quad * 8;
        bf16x8 wh = *(const bf16x8*)&Wh[gw];
        bf16x8 wl = *(const bf16x8*)&Wl[gw];
        acc[u] = __builtin_amdgcn_mfma_f32_16x16x32_bf16(xh[kc], wh, acc[u], 0, 0, 0);
        acc[u] = __builtin_amdgcn_mfma_f32_16x16x32_bf16(xh[kc], wl, acc[u], 0, 0, 0);
        acc[u] = __builtin_amdgcn_mfma_f32_16x16x32_bf16(xl_[kc], wh, acc[u], 0, 0, 0);
      }
    }
#pragma unroll
    for (int u = 0; u < 4; u++) {
      int col = (ng + u) * 16 + n;
      float bv = (col >= O) ? bias[col - O] : 0.f;
#pragma unroll
      for (int r = 0; r < 4; r++) {
        int row = m0 + quad * 4 + r;
        Y[(size_t)row * N2 + col] = acc[u][r] + bv;
      }
    }
  }
}

// ---------------- small GEMM for layer 1 (K=3, fp32) ----------------
__global__ __launch_bounds__(256) void gemm_k(const float* __restrict__ A,
                                              const float* __restrict__ Wc,
                                              const float* __restrict__ bias,
                                              float* __restrict__ Y, int K, int N2,
                                              int O) {
  __shared__ float As[8 * 68];
  __shared__ float Bs[8 * 68];
  int tid = threadIdx.x;
  int n0 = blockIdx.x * 64;
  int m0 = blockIdx.y * 64;
  int tx = tid & 15, ty = tid >> 4;
  float acc[4][4] = {};
  for (int k0 = 0; k0 < K; k0 += 8) {
    __syncthreads();
    {
      int e = tid, mm = e >> 3, kk = e & 7;
      As[kk * 68 + mm] = (k0 + kk < K) ? A[(size_t)(m0 + mm) * K + k0 + kk] : 0.f;
      int nn = mm;
      Bs[kk * 68 + nn] = (k0 + kk < K) ? Wc[(size_t)(n0 + nn) * K + k0 + kk] : 0.f;
      e = tid + 256;
      mm = e >> 3;
      kk = e & 7;
      As[kk * 68 + mm] = (k0 + kk < K) ? A[(size_t)(m0 + mm) * K + k0 + kk] : 0.f;
      nn = mm;
      Bs[kk * 68 + nn] = (k0 + kk < K) ? Wc[(size_t)(n0 + nn) * K + k0 + kk] : 0.f;
    }
    __syncthreads();
#pragma unroll
    for (int kk = 0; kk < 8; kk++) {
      float4 av = *(float4*)&As[kk * 68 + ty * 4];
      float4 bv = *(float4*)&Bs[kk * 68 + tx * 4];
      float a[4] = {av.x, av.y, av.z, av.w};
      float bb2[4] = {bv.x, bv.y, bv.z, bv.w};
#pragma unroll
      for (int ii = 0; ii < 4; ii++)
#pragma unroll
        for (int jj = 0; jj < 4; jj++) acc[ii][jj] += a[ii] * bb2[jj];
    }
  }
  int col = n0 + tx * 4;
  bool isV = (col >= O);
  float b0 = 0.f, b1 = 0.f, b2 = 0.f, b3 = 0.f;
  if (isV) {
    b0 = bias[col + 0 - O];
    b1 = bias[col + 1 - O];
    b2 = bias[col + 2 - O];
    b3 = bias[col + 3 - O];
  }
#pragma unroll
  for (int ii = 0; ii < 4; ii++) {
    int row = m0 + ty * 4 + ii;
    float4 o4;
    o4.x = acc[ii][0] + b0;
    o4.y = acc[ii][1] + b1;
    o4.z = acc[ii][2] + b2;
    o4.w = acc[ii][3] + b3;
    *(float4*)&Y[(size_t)row * N2 + col] = o4;
  }
}

// ---------------- gather + max + LeakyReLU + FUSED next-layer cvt/sqh ------
// (r12-verified) CN != 0: also emit split-bf16 of the output (next layer's
// Xhi/Xlo) and half-norms sqh (T-lane butterfly, T = O/4).
template <int O, int CN>
__global__ __launch_bounds__(256) void gmax_v(const float* __restrict__ Y,
                                              const int* __restrict__ idx,
                                              float* __restrict__ out,
                                              ushort* __restrict__ nxh,
                                              ushort* __restrict__ nxl,
                                              float* __restrict__ nsq) {
  constexpr int T = O / 4;
  constexpr int G = 256 / T;
  int tid = threadIdx.x;
  int p = blockIdx.x * G + tid / T;
  int o4 = (tid % T) * 4;
  int b = p >> 12;
  constexpr int N2 = 2 * O;
  const int* ip = idx + (size_t)p * KNN;
  float4 m = make_float4(NEG_INF, NEG_INF, NEG_INF, NEG_INF);
#pragma unroll
  for (int k = 0; k < KNN; k++) {
    int j = ip[k];
    float4 v = *(const float4*)&Y[((size_t)(b * NTOT + j)) * N2 + o4];
    m.x = fmaxf(m.x, v.x);
    m.y = fmaxf(m.y, v.y);
    m.z = fmaxf(m.z, v.z);
    m.w = fmaxf(m.w, v.w);
  }
  float4 c = *(const float4*)&Y[(size_t)p * N2 + O + o4];
  float4 o;
  o.x = c.x + m.x;
  o.y = c.y + m.y;
  o.z = c.z + m.z;
  o.w = c.w + m.w;
  o.x = (o.x >= 0.f) ? o.x : 0.2f * o.x;
  o.y = (o.y >= 0.f) ? o.y : 0.2f * o.y;
  o.z = (o.z >= 0.f) ? o.z : 0.2f * o.z;
  o.w = (o.w >= 0.f) ? o.w : 0.2f * o.w;
  *(float4*)&out[(size_t)p * O + o4] = o;

  if constexpr (CN != 0) {
    ushort4 h4, l4;
    sbf16(o.x, h4.x, l4.x);
    sbf16(o.y, h4.y, l4.y);
    sbf16(o.z, h4.z, l4.z);
    sbf16(o.w, h4.w, l4.w);
    *(ushort4*)&nxh[(size_t)p * O + o4] = h4;
    *(ushort4*)&nxl[(size_t)p * O + o4] = l4;
    float ss = o.x * o.x + o.y * o.y + o.z * o.z + o.w * o.w;
#pragma unroll
    for (int s = 1; s < T; s <<= 1) ss += __shfl_xor(ss, s);
    if ((tid & (T - 1)) == 0) nsq[p] = 0.5f * ss;
  }
}

// ---------------- host side ----------------
template <int C, int O, int CN>
static void run_layer(const float* fin, void* const* w5, float* fout, float* Wc,
                      float* biasb, ushort* Wch, ushort* Wcl, int* idx, float* Y,
                      float* sqh, unsigned* cval, ushort* Xhi, ushort* Xlo,
                      ushort* nxh, ushort* nxl, hipStream_t stream) {
  const float* W = (const float*)w5[0];
  const float* g = (const float*)w5[1];
  const float* bb = (const float*)w5[2];
  const float* mm = (const float*)w5[3];
  const float* vv = (const float*)w5[4];
  int N2 = 2 * O;
  prep_w<<<(2 * O * C + 255) / 256, 256, 0, stream>>>(W, g, bb, mm, vv, Wc,
                                                      biasb, Wch, Wcl, O, C);
  if constexpr (C == 3) {
    cvt3_k<<<NBATCH * NTOT * 32 / 256, 256, 0, stream>>>(fin, Xhi, Xlo);
    sqh3_k<<<NBATCH * NTOT / 256, 256, 0, stream>>>(fin, sqh);
    knn_m<32><<<NBATCH * 32 * (JSPLIT / 2), 512, 0, stream>>>(Xhi, Xlo, sqh, cval);
    kref_w<3, 512><<<NBATCH * NTOT / 8, 256, 0, stream>>>(fin, cval, idx);
    dim3 gg(N2 / 64, NBATCH * NTOT / 64);
    gemm_k<<<gg, 256, 0, stream>>>(fin, Wc, biasb, Y, C, N2, O);
  } else if constexpr (CN == 0) {
    // FINAL layer: MFMA gemm (no downstream KNN -> precision margin safe)
    knn_m<C><<<NBATCH * 32 * (JSPLIT / 2), 512, 0, stream>>>(Xhi, Xlo, sqh, cval);
    kref_w<C, 512><<<NBATCH * NTOT / 8, 256, 0, stream>>>(fin, cval, idx);
    gemm_m<C, 2 * O><<<NBATCH * NTOT / 64, 256, 0, stream>>>(Xhi, Xlo, Wch, Wcl,
                                                             biasb, Y);
  } else {
    // mid layers: fp32 gemm (activations feed next layer's KNN)
    knn_m<C><<<NBATCH * 32 * (JSPLIT / 2), 512, 0, stream>>>(Xhi, Xlo, sqh, cval);
    kref_w<C, 512><<<NBATCH * NTOT / 8, 256, 0, stream>>>(fin, cval, idx);
    dim3 gg(N2 / 128, NBATCH * NTOT / 128);
    gemm128<<<gg, 256, 0, stream>>>(fin, Wc, biasb, Y, C, N2, O);
  }
  gmax_v<O, CN><<<NBATCH * NTOT / (256 / (O / 4)), 256, 0, stream>>>(
      Y, idx, fout, nxh, nxl, sqh);
}

extern "C" void kernel_launch(void* const* d_in, const int* in_sizes, int n_in,
                              void* d_out, int out_size, void* d_ws, size_t ws_size,
                              hipStream_t stream) {
  const float* x = (const float*)d_in[0];
  char* ws = (char*)d_ws;
  float* Wc = (float*)(ws + 0);            // 262144
  float* biasb = (float*)(ws + 262144);    // 1024
  int* idx = (int*)(ws + 263168);          // 1310720
  float* sqh = (float*)(ws + 1573888);     // 65536
  float* Y = (float*)(ws + 1639424);       // 33554432 -> ends 35193856
  float* x1 = (float*)(ws + 35193856);     // 4194304
  float* x2 = (float*)(ws + 39388160);     // 4194304
  float* x3 = (float*)(ws + 43582464);     // 8388608 -> ends 51971072
  ushort* Wch = (ushort*)(ws + 51971072);  // 131072 (max 2*O*C = 65536 elems)
  ushort* Wcl = (ushort*)(ws + 52102144);  // 131072 -> ends 52233216

  // cval (512 slots/point = 32MB) aliases Y (consumed by kref_w before gemm).
  unsigned* cval = (unsigned*)Y;
  // Xhi/Xlo live in each layer's OUTPUT buffer (dead until gmax_v writes it):
  ushort* X1h = (ushort*)x1;                          // layer1: C=32 pad -> 1MB+1MB
  ushort* X1l = X1h + (size_t)NBATCH * NTOT * 32;
  ushort* X2h = (ushort*)x2;                          // layer2: C=64 -> 2MB+2MB
  ushort* X2l = X2h + (size_t)NBATCH * NTOT * 64;
  ushort* X3h = (ushort*)x3;                          // layer3: C=64 -> 2MB+2MB
  ushort* X3l = X3h + (size_t)NBATCH * NTOT * 64;
  float* outf = (float*)d_out;
  ushort* X4h = (ushort*)outf;                        // layer4: C=128 -> 4MB+4MB
  ushort* X4l = X4h + (size_t)NBATCH * NTOT * 128;

  run_layer<3, 64, 64>(x, d_in + 1, x1, Wc, biasb, Wch, Wcl, idx, Y, sqh, cval,
                       X1h, X1l, X2h, X2l, stream);
  run_layer<64, 64, 64>(x1, d_in + 6, x2, Wc, biasb, Wch, Wcl, idx, Y, sqh, cval,
                        X2h, X2l, X3h, X3l, stream);
  run_layer<64, 128, 128>(x2, d_in + 11, x3, Wc, biasb, Wch, Wcl, idx, Y, sqh,
                          cval, X3h, X3l, X4h, X4l, stream);
  run_layer<128, 256, 0>(x3, d_in + 16, outf, Wc, biasb, Wch, Wcl, idx, Y, sqh,
                         cval, X4h, X4l, nullptr, nullptr, stream);
}

// Round 19
// 649.534 us; speedup vs baseline: 1.1035x; 1.1035x over previous
//
#include <hip/hip_runtime.h>

#define NTOT 4096
#define NBATCH 4
#define KNN 20
#define JSPLIT 8
#define KMRG 24
#define CSLOTM 512  // MFMA-path candidate slots per point (64 lists x 8)

constexpr float NEG_INF = -3.0e38f;

typedef __attribute__((ext_vector_type(8))) short bf16x8;
typedef __attribute__((ext_vector_type(4))) float f32x4;

__device__ __forceinline__ unsigned pk(float f, int j) {
  unsigned u = __float_as_uint(f);
  u = (u & 0x80000000u) ? ~u : (u | 0x80000000u);
  return (u & 0xFFFFF000u) | (unsigned)j;
}

__device__ __forceinline__ void pins8(unsigned u, unsigned (&tv)[8]) {
  if (u > tv[0]) {
    tv[0] = u;
#pragma unroll
    for (int x = 1; x < 8; x++) {
      unsigned mn = min(tv[0], tv[x]);
      unsigned mx = max(tv[0], tv[x]);
      tv[0] = mn;
      tv[x] = mx;
    }
  }
}

// split-bf16: x = hi + lo (round-to-nearest-even at each step)
__device__ __forceinline__ void sbf16(float x, ushort& h16, ushort& l16) {
  unsigned u = __float_as_uint(x);
  unsigned h = (u + 0x7FFFu + ((u >> 16) & 1u)) >> 16;
  float hf = __uint_as_float(h << 16);
  float r = x - hf;
  unsigned v = __float_as_uint(r);
  unsigned l = (v + 0x7FFFu + ((v >> 16) & 1u)) >> 16;
  h16 = (ushort)h;
  l16 = (ushort)l;
}

// async global->LDS 16B copy (lane i writes lds + i*16)
__device__ __forceinline__ void gll16(const void* g, void* l) {
  __builtin_amdgcn_global_load_lds(
      (const __attribute__((address_space(1))) unsigned int*)g,
      (__attribute__((address_space(3))) unsigned int*)l, 16, 0, 0);
}

// ---------------- prep: fold BN scale into weights ----------------
__global__ void prep_w(const float* __restrict__ W, const float* __restrict__ gg,
                       const float* __restrict__ bb, const float* __restrict__ mm,
                       const float* __restrict__ vv, float* __restrict__ Wc,
                       float* __restrict__ bias, int O, int C) {
  int t = blockIdx.x * 256 + threadIdx.x;
  if (t >= 2 * O * C) return;
  int o2 = t / C, c = t - o2 * C;
  int o = (o2 < O) ? o2 : o2 - O;
  float s = gg[o] * rsqrtf(vv[o] + 1e-5f);
  float w = (o2 < O) ? W[o * 2 * C + c] * s
                     : (W[o * 2 * C + C + c] - W[o * 2 * C + c]) * s;
  Wc[o2 * C + c] = w;
  if (o2 >= O && c == 0) bias[o] = bb[o] - mm[o] * s;
}

// layer-1: (B,N,3) fp32 -> (B,N,32) split-bf16 (dims 3..31 zero) + sqh fused
__global__ void cvt3_k(const float* __restrict__ f, ushort* __restrict__ hi,
                       ushort* __restrict__ lo, float* __restrict__ sqh) {
  int p = blockIdx.x * 256 + threadIdx.x;  // over NBATCH*NTOT*32
  int pt = p >> 5, dim = p & 31;
  float x = (dim < 3) ? f[pt * 3 + dim] : 0.f;
  ushort h16, l16;
  sbf16(x, h16, l16);
  hi[p] = h16;
  lo[p] = l16;
  if (dim == 0) {
    float a = x;
    float b2 = f[pt * 3 + 1];
    float c = f[pt * 3 + 2];
    sqh[pt] = 0.5f * (a * a + b2 * b2 + c * c);
  }
}

// ---------------- KNN stage 1: pipelined gll + swapped MFMA, js-pair -------
// (r12/r14-verified 512-thread form; 8 waves/block, 2 blocks/CU sweet spot)
template <int C>
__global__ __launch_bounds__(512, 4) void knn_m(const ushort* __restrict__ Xhi,
                                                const ushort* __restrict__ Xlo,
                                                const float* __restrict__ sqh,
                                                unsigned* __restrict__ cval) {
  constexpr int NK = C / 32;
  constexpr int NJT = NTOT / (128 * JSPLIT);  // 4
  constexpr int NSQ = 2 * NJT;                // 8 seq j-tiles (js pair)
  __shared__ __align__(16) char smem[69632];  // 2x32KB bufs + sqB 4KB
  float* sqB = (float*)(smem + 65536);

  int tid = threadIdx.x;
  int raw = blockIdx.x;  // 512 blocks: [itHi(4)|jsp(2)|it0(1)|b(2)]
  int b = raw & 3;
  int jsp = (raw >> 3) & 3;
  int it = (((raw >> 5) & 15) << 1) | ((raw >> 2) & 1);
  int i0 = it * 128;
  int jpbase = jsp * 1024;
  const ushort* xh = Xhi + (size_t)b * NTOT * C;
  const ushort* xl = Xlo + (size_t)b * NTOT * C;

  int l = tid & 63, wid = tid >> 6;  // wid 0..7
  int wi = wid & 3, wj = wid >> 2;
  int n = l & 15, quad = l >> 4;
  int xr16 = (n & 7) << 4;  // read-side XOR ((row&7)<<4; row&7 == n&7)

  // gll source decode: stored chunk c = (R*4+q) ^ (R&7); invert for c = lane
  int t0 = l & 1, t1 = (l >> 1) & 1, t2 = (l >> 2) & 1, t3 = (l >> 3) & 1,
      t4 = (l >> 4) & 1, t5 = (l >> 5) & 1;
  int Rl = (t2 ^ t4) | (t3 << 1) | (t4 << 2) | (t5 << 3);
  int ql = (t0 ^ t2 ^ t4) | ((t1 ^ t3) << 1);

  if (tid < 256) {
    float4 s4 = *(const float4*)&sqh[b * NTOT + jpbase + tid * 4];
    *(float4*)&sqB[tid * 4] = s4;
  }
  __syncthreads();  // publish sqB + drain its load before counted-vmcnt phase

  unsigned tv[2][8];
#pragma unroll
  for (int ti = 0; ti < 2; ti++)
#pragma unroll
    for (int x = 0; x < 8; x++) tv[ti][x] = 0u;

  // 4 glls per wave per chunk: {Ah,Al,Bh,Bl} x 1 band of 16 rows (band=wid)
  auto issue = [&](int sn, int kcn, char* buf) {
    int j0n = jpbase + sn * 128;
    int R = Rl + wid * 16;
    size_t gA = (size_t)(i0 + R) * C + kcn + ql * 8;
    size_t gB = (size_t)(j0n + R) * C + kcn + ql * 8;
    char* ld = buf + wid * 1024;
    gll16(xh + gA, ld);            // Ah
    gll16(xl + gA, ld + 8192);     // Al
    gll16(xh + gB, ld + 16384);    // Bh
    gll16(xl + gB, ld + 24576);    // Bl
  };

  issue(0, 0, smem);  // prologue: chunk 0 -> buf0

  int g = 0;
  for (int s = 0; s < NSQ; s++) {
    int j0 = jpbase + s * 128;

    f32x4 acc[4][2];  // [tj][ti]: j in regs, i = lane col
#pragma unroll
    for (int tj = 0; tj < 4; tj++)
#pragma unroll
      for (int ti = 0; ti < 2; ti++) acc[tj][ti] = (f32x4)(0.f);

    for (int kc = 0; kc < NK; kc++) {
      __builtin_amdgcn_s_barrier();  // (A) all waves done reading target buf
      int nsn = (kc + 1 < NK) ? s : ((s + 1 == NSQ) ? 0 : s + 1);
      int nkc = (kc + 1 < NK) ? (kc + 1) * 32 : 0;
      issue(nsn, nkc, smem + ((g + 1) & 1) * 32768);
      asm volatile("s_waitcnt vmcnt(4)" ::: "memory");  // chunk g landed
      __builtin_amdgcn_s_barrier();                     // (C) data visible
      const char* bc = smem + (g & 1) * 32768;

      bf16x8 ah[2], al_[2];
#pragma unroll
      for (int ti = 0; ti < 2; ti++) {
        int row = wi * 32 + ti * 16 + n;
        int off = (row * 64 + quad * 16) ^ xr16;
        ah[ti] = *(const bf16x8*)(bc + off);
        al_[ti] = *(const bf16x8*)(bc + 8192 + off);
      }
#pragma unroll
      for (int tj = 0; tj < 4; tj++) {
        int row = wj * 64 + tj * 16 + n;
        int off = (row * 64 + quad * 16) ^ xr16;
        bf16x8 bh = *(const bf16x8*)(bc + 16384 + off);
        bf16x8 bl = *(const bf16x8*)(bc + 24576 + off);
#pragma unroll
        for (int ti = 0; ti < 2; ti++) {
          acc[tj][ti] = __builtin_amdgcn_mfma_f32_16x16x32_bf16(bh, ah[ti], acc[tj][ti], 0, 0, 0);
          acc[tj][ti] = __builtin_amdgcn_mfma_f32_16x16x32_bf16(bh, al_[ti], acc[tj][ti], 0, 0, 0);
          acc[tj][ti] = __builtin_amdgcn_mfma_f32_16x16x32_bf16(bl, ah[ti], acc[tj][ti], 0, 0, 0);
        }
      }
      g++;
    }

    float4 sq4[4];
#pragma unroll
    for (int tj = 0; tj < 4; tj++)
      sq4[tj] = *(const float4*)&sqB[s * 128 + wj * 64 + tj * 16 + quad * 4];
#pragma unroll
    for (int ti = 0; ti < 2; ti++) {
#pragma unroll
      for (int tj = 0; tj < 4; tj++) {
        float v0 = acc[tj][ti][0] - sq4[tj].x;
        float v1 = acc[tj][ti][1] - sq4[tj].y;
        float v2 = acc[tj][ti][2] - sq4[tj].z;
        float v3 = acc[tj][ti][3] - sq4[tj].w;
        float m4 = fmaxf(fmaxf(v0, v1), fmaxf(v2, v3));
        if (pk(m4, 0xFFF) > tv[ti][0]) {
          int jb = j0 + wj * 64 + tj * 16 + quad * 4;
          pins8(pk(v0, jb + 0), tv[ti]);
          pins8(pk(v1, jb + 1), tv[ti]);
          pins8(pk(v2, jb + 2), tv[ti]);
          pins8(pk(v3, jb + 3), tv[ti]);
        }
      }
    }

    // js-phase boundary: write out lists for this js, reset tv
    if (s == NJT - 1 || s == NSQ - 1) {
      int js = jsp * 2 + ((s == NSQ - 1) ? 1 : 0);
#pragma unroll
      for (int ti = 0; ti < 2; ti++) {
        int p = b * NTOT + i0 + wi * 32 + ti * 16 + n;
        unsigned* dst = cval + (size_t)p * CSLOTM + js * 64 + wj * 32 + quad * 8;
        uint4 o0, o1;
        o0.x = tv[ti][0]; o0.y = tv[ti][1]; o0.z = tv[ti][2]; o0.w = tv[ti][3];
        o1.x = tv[ti][4]; o1.y = tv[ti][5]; o1.z = tv[ti][6]; o1.w = tv[ti][7];
        *(uint4*)&dst[0] = o0;
        *(uint4*)&dst[4] = o1;
#pragma unroll
        for (int x = 0; x < 8; x++) tv[ti][x] = 0u;
      }
    }
  }
}

// ---------------- wave-per-2-points merge + refine + bitonic top-20 --------
// (r13/r14-verified) ILP-2: each wave processes TWO points with the pt loop
// INSIDE each stage so the two independent shuffle chains interleave.
template <int C, int NC>
__global__ __launch_bounds__(256) void kref_w(const float* __restrict__ feat,
                                              const unsigned* __restrict__ cval,
                                              int* __restrict__ outidx) {
  int tid = threadIdx.x;
  int lane = tid & 63;
  int pbase = blockIdx.x * 8 + (tid >> 6) * 2;

  unsigned c[2][8];
  int bq[2], iq[2];
#pragma unroll
  for (int pt = 0; pt < 2; pt++) {
    int p = pbase + pt;
    bq[pt] = p >> 12;
    iq[pt] = p & (NTOT - 1);
    uint4 aa = *(const uint4*)&cval[(size_t)p * NC + lane * 8];
    uint4 bb2 = *(const uint4*)&cval[(size_t)p * NC + lane * 8 + 4];
    c[pt][0] = aa.x; c[pt][1] = aa.y; c[pt][2] = aa.z; c[pt][3] = aa.w;
    c[pt][4] = bb2.x; c[pt][5] = bb2.y; c[pt][6] = bb2.z; c[pt][7] = bb2.w;
  }

  // sort each lane-list descending: optimal 19-CE network (c[0] = max)
#define CE(a, bq2)                          \
  {                                         \
    unsigned mx = max(c[pt][a], c[pt][bq2]); \
    unsigned mn = min(c[pt][a], c[pt][bq2]); \
    c[pt][a] = mx;                          \
    c[pt][bq2] = mn;                        \
  }
#pragma unroll
  for (int pt = 0; pt < 2; pt++) {
    CE(0, 1) CE(2, 3) CE(4, 5) CE(6, 7)
    CE(0, 2) CE(1, 3) CE(4, 6) CE(5, 7)
    CE(1, 2) CE(5, 6) CE(0, 4) CE(3, 7)
    CE(1, 5) CE(2, 6)
    CE(1, 4) CE(3, 6)
    CE(2, 4) CE(3, 5)
    CE(3, 4)
  }
#undef CE

  int myj[2] = {-1, -1};
#pragma unroll
  for (int t = 0; t < KMRG; t++) {
#pragma unroll
    for (int pt = 0; pt < 2; pt++) {
      unsigned m = c[pt][0];
#pragma unroll
      for (int s = 1; s < 64; s <<= 1)
        m = max(m, (unsigned)__shfl_xor((int)m, s));
      if (lane == t) myj[pt] = (int)(m & 0xFFFu);
      bool mine = (c[pt][0] == m);
      c[pt][0] = mine ? c[pt][1] : c[pt][0];
      c[pt][1] = mine ? c[pt][2] : c[pt][1];
      c[pt][2] = mine ? c[pt][3] : c[pt][2];
      c[pt][3] = mine ? c[pt][4] : c[pt][3];
      c[pt][4] = mine ? c[pt][5] : c[pt][4];
      c[pt][5] = mine ? c[pt][6] : c[pt][5];
      c[pt][6] = mine ? c[pt][7] : c[pt][6];
      c[pt][7] = mine ? 0u : c[pt][7];
    }
  }

  float myval[2] = {NEG_INF, NEG_INF};
  if constexpr (C == 3) {
#pragma unroll
    for (int pt = 0; pt < 2; pt++) {
      const float* fb = feat + (size_t)bq[pt] * NTOT * 3;
      if (lane < KMRG) {
        float x0 = fb[(size_t)iq[pt] * 3 + 0];
        float x1 = fb[(size_t)iq[pt] * 3 + 1];
        float x2 = fb[(size_t)iq[pt] * 3 + 2];
        float y0 = fb[(size_t)myj[pt] * 3 + 0];
        float y1 = fb[(size_t)myj[pt] * 3 + 1];
        float y2 = fb[(size_t)myj[pt] * 3 + 2];
        float d0 = x0 - y0, d1 = x1 - y1, d2 = x2 - y2;
        myval[pt] = -(d0 * d0 + d1 * d1 + d2 * d2);
      }
    }
  } else {
    constexpr int SL = C / 8;  // dims per lane within 8-lane group (8 or 16)
    int m8 = lane & 7;
    float4 xs[2][SL / 4];
#pragma unroll
    for (int pt = 0; pt < 2; pt++)
#pragma unroll
      for (int q4 = 0; q4 < SL / 4; q4++)
        xs[pt][q4] = *(const float4*)&feat[((size_t)bq[pt] * NTOT + iq[pt]) * C +
                                           m8 * SL + q4 * 4];
#pragma unroll
    for (int ps = 0; ps < KMRG / 8; ps++) {
      int src = ps * 8 + (lane >> 3);
#pragma unroll
      for (int pt = 0; pt < 2; pt++) {
        int j = __shfl(myj[pt], src);
        float d = 0.f;
#pragma unroll
        for (int q4 = 0; q4 < SL / 4; q4++) {
          float4 yv = *(const float4*)&feat[((size_t)bq[pt] * NTOT + j) * C +
                                            m8 * SL + q4 * 4];
          float dx = xs[pt][q4].x - yv.x;
          float dy = xs[pt][q4].y - yv.y;
          float dz = xs[pt][q4].z - yv.z;
          float dw = xs[pt][q4].w - yv.w;
          d += dx * dx + dy * dy + dz * dz + dw * dw;
        }
#pragma unroll
        for (int s = 1; s < 8; s <<= 1) d += __shfl_xor(d, s);
        float sd = __shfl(d, (lane & 7) << 3);
        bool upd = ((lane >> 3) == ps);
        myval[pt] = upd ? -sd : myval[pt];
      }
    }
  }

  // bitonic sort, 64 lanes, descending (lane 0 = best); ties -> smaller idx
#pragma unroll
  for (int k = 2; k <= 64; k <<= 1) {
#pragma unroll
    for (int j2 = k >> 1; j2 > 0; j2 >>= 1) {
#pragma unroll
      for (int pt = 0; pt < 2; pt++) {
        float ov = __shfl_xor(myval[pt], j2);
        int oj = __shfl_xor(myj[pt], j2);
        bool ogt = (ov > myval[pt]) || (ov == myval[pt] && oj < myj[pt]);
        bool lower = ((lane & j2) == 0);
        bool desc = ((lane & k) == 0);
        bool take = (desc == (lower == ogt));
        myval[pt] = take ? ov : myval[pt];
        myj[pt] = take ? oj : myj[pt];
      }
    }
  }

#pragma unroll
  for (int pt = 0; pt < 2; pt++)
    if (lane < KNN) outidx[(size_t)(pbase + pt) * KNN + lane] = myj[pt];
}

// ---------------- 128x128 fp32 GEMM (layers 2-4): Y = A * Wc^T -------------
// (r14-verified; fp32 activations are load-bearing for downstream KNN tie
// stability, and the LDS-tiled fp32 form beat both gemm_m variants.)
__global__ __launch_bounds__(256) void gemm128(const float* __restrict__ A,
                                               const float* __restrict__ Wc,
                                               const float* __restrict__ bias,
                                               float* __restrict__ Y, int K, int N2,
                                               int O) {
  constexpr int P = 140;
  __shared__ float As[16 * P];
  __shared__ float Bs[16 * P];
  int tid = threadIdx.x;
  int n0 = blockIdx.x * 128;
  int m0 = blockIdx.y * 128;
  int tx = tid & 15, ty = tid >> 4;
  int aoff = (ty * 8) + (((ty * 8) >> 5) << 2);
  int boff = (tx * 8) + (((tx * 8) >> 5) << 2);
  float acc[8][8];
#pragma unroll
  for (int ii = 0; ii < 8; ii++)
#pragma unroll
    for (int jj = 0; jj < 8; jj++) acc[ii][jj] = 0.f;

  for (int kc = 0; kc < K; kc += 16) {
    __syncthreads();
#pragma unroll
    for (int l = 0; l < 2; l++) {
      int e = tid + 256 * l;
      int rr = e >> 2, c4 = e & 3;
      int sc = rr + ((rr >> 5) << 2);
      float4 va = *(const float4*)&A[(size_t)(m0 + rr) * K + kc + c4 * 4];
      As[(c4 * 4 + 0) * P + sc] = va.x;
      As[(c4 * 4 + 1) * P + sc] = va.y;
      As[(c4 * 4 + 2) * P + sc] = va.z;
      As[(c4 * 4 + 3) * P + sc] = va.w;
      float4 vb = *(const float4*)&Wc[(size_t)(n0 + rr) * K + kc + c4 * 4];
      Bs[(c4 * 4 + 0) * P + sc] = vb.x;
      Bs[(c4 * 4 + 1) * P + sc] = vb.y;
      Bs[(c4 * 4 + 2) * P + sc] = vb.z;
      Bs[(c4 * 4 + 3) * P + sc] = vb.w;
    }
    __syncthreads();
#pragma unroll 8
    for (int k = 0; k < 16; k++) {
      float4 a0 = *(const float4*)&As[k * P + aoff];
      float4 a1 = *(const float4*)&As[k * P + aoff + 4];
      float4 b0 = *(const float4*)&Bs[k * P + boff];
      float4 b1 = *(const float4*)&Bs[k * P + boff + 4];
      float av[8] = {a0.x, a0.y, a0.z, a0.w, a1.x, a1.y, a1.z, a1.w};
      float bv[8] = {b0.x, b0.y, b0.z, b0.w, b1.x, b1.y, b1.z, b1.w};
#pragma unroll
      for (int ii = 0; ii < 8; ii++)
#pragma unroll
        for (int jj = 0; jj < 8; jj++)
          acc[ii][jj] = fmaf(av[ii], bv[jj], acc[ii][jj]);
    }
  }

  int col0 = n0 + tx * 8;
  float bv[8];
#pragma unroll
  for (int jj = 0; jj < 8; jj++) {
    int col = col0 + jj;
    bv[jj] = (col >= O) ? bias[col - O] : 0.f;
  }
#pragma unroll
  for (int ii = 0; ii < 8; ii++) {
    int row = m0 + ty * 8 + ii;
    float4 o0, o1;
    o0.x = acc[ii][0] + bv[0];
    o0.y = acc[ii][1] + bv[1];
    o0.z = acc[ii][2] + bv[2];
    o0.w = acc[ii][3] + bv[3];
    o1.x = acc[ii][4] + bv[4];
    o1.y = acc[ii][5] + bv[5];
    o1.z = acc[ii][6] + bv[6];
    o1.w = acc[ii][7] + bv[7];
    *(float4*)&Y[(size_t)row * N2 + col0] = o0;
    *(float4*)&Y[(size_t)row * N2 + col0 + 4] = o1;
  }
}

// ---------------- small GEMM for layer 1 (K=3, fp32) ----------------
__global__ __launch_bounds__(256) void gemm_k(const float* __restrict__ A,
                                              const float* __restrict__ Wc,
                                              const float* __restrict__ bias,
                                              float* __restrict__ Y, int K, int N2,
                                              int O) {
  __shared__ float As[8 * 68];
  __shared__ float Bs[8 * 68];
  int tid = threadIdx.x;
  int n0 = blockIdx.x * 64;
  int m0 = blockIdx.y * 64;
  int tx = tid & 15, ty = tid >> 4;
  float acc[4][4] = {};
  for (int k0 = 0; k0 < K; k0 += 8) {
    __syncthreads();
    {
      int e = tid, mm = e >> 3, kk = e & 7;
      As[kk * 68 + mm] = (k0 + kk < K) ? A[(size_t)(m0 + mm) * K + k0 + kk] : 0.f;
      int nn = mm;
      Bs[kk * 68 + nn] = (k0 + kk < K) ? Wc[(size_t)(n0 + nn) * K + k0 + kk] : 0.f;
      e = tid + 256;
      mm = e >> 3;
      kk = e & 7;
      As[kk * 68 + mm] = (k0 + kk < K) ? A[(size_t)(m0 + mm) * K + k0 + kk] : 0.f;
      nn = mm;
      Bs[kk * 68 + nn] = (k0 + kk < K) ? Wc[(size_t)(n0 + nn) * K + k0 + kk] : 0.f;
    }
    __syncthreads();
#pragma unroll
    for (int kk = 0; kk < 8; kk++) {
      float4 av = *(float4*)&As[kk * 68 + ty * 4];
      float4 bv = *(float4*)&Bs[kk * 68 + tx * 4];
      float a[4] = {av.x, av.y, av.z, av.w};
      float bb2[4] = {bv.x, bv.y, bv.z, bv.w};
#pragma unroll
      for (int ii = 0; ii < 4; ii++)
#pragma unroll
        for (int jj = 0; jj < 4; jj++) acc[ii][jj] += a[ii] * bb2[jj];
    }
  }
  int col = n0 + tx * 4;
  bool isV = (col >= O);
  float b0 = 0.f, b1 = 0.f, b2 = 0.f, b3 = 0.f;
  if (isV) {
    b0 = bias[col + 0 - O];
    b1 = bias[col + 1 - O];
    b2 = bias[col + 2 - O];
    b3 = bias[col + 3 - O];
  }
#pragma unroll
  for (int ii = 0; ii < 4; ii++) {
    int row = m0 + ty * 4 + ii;
    float4 o4;
    o4.x = acc[ii][0] + b0;
    o4.y = acc[ii][1] + b1;
    o4.z = acc[ii][2] + b2;
    o4.w = acc[ii][3] + b3;
    *(float4*)&Y[(size_t)row * N2 + col] = o4;
  }
}

// ---------------- gather + max + LeakyReLU + FUSED next-layer cvt/sqh ------
// (r12/r14-verified) CN != 0: also emit split-bf16 of the output (next
// layer's Xhi/Xlo) and half-norms sqh (T-lane butterfly, T = O/4).
template <int O, int CN>
__global__ __launch_bounds__(256) void gmax_v(const float* __restrict__ Y,
                                              const int* __restrict__ idx,
                                              float* __restrict__ out,
                                              ushort* __restrict__ nxh,
                                              ushort* __restrict__ nxl,
                                              float* __restrict__ nsq) {
  constexpr int T = O / 4;
  constexpr int G = 256 / T;
  int tid = threadIdx.x;
  int p = blockIdx.x * G + tid / T;
  int o4 = (tid % T) * 4;
  int b = p >> 12;
  constexpr int N2 = 2 * O;
  const int* ip = idx + (size_t)p * KNN;
  float4 m = make_float4(NEG_INF, NEG_INF, NEG_INF, NEG_INF);
#pragma unroll
  for (int k = 0; k < KNN; k++) {
    int j = ip[k];
    float4 v = *(const float4*)&Y[((size_t)(b * NTOT + j)) * N2 + o4];
    m.x = fmaxf(m.x, v.x);
    m.y = fmaxf(m.y, v.y);
    m.z = fmaxf(m.z, v.z);
    m.w = fmaxf(m.w, v.w);
  }
  float4 c = *(const float4*)&Y[(size_t)p * N2 + O + o4];
  float4 o;
  o.x = c.x + m.x;
  o.y = c.y + m.y;
  o.z = c.z + m.z;
  o.w = c.w + m.w;
  o.x = (o.x >= 0.f) ? o.x : 0.2f * o.x;
  o.y = (o.y >= 0.f) ? o.y : 0.2f * o.y;
  o.z = (o.z >= 0.f) ? o.z : 0.2f * o.z;
  o.w = (o.w >= 0.f) ? o.w : 0.2f * o.w;
  *(float4*)&out[(size_t)p * O + o4] = o;

  if constexpr (CN != 0) {
    ushort4 h4, l4;
    sbf16(o.x, h4.x, l4.x);
    sbf16(o.y, h4.y, l4.y);
    sbf16(o.z, h4.z, l4.z);
    sbf16(o.w, h4.w, l4.w);
    *(ushort4*)&nxh[(size_t)p * O + o4] = h4;
    *(ushort4*)&nxl[(size_t)p * O + o4] = l4;
    float ss = o.x * o.x + o.y * o.y + o.z * o.z + o.w * o.w;
#pragma unroll
    for (int s = 1; s < T; s <<= 1) ss += __shfl_xor(ss, s);
    if ((tid & (T - 1)) == 0) nsq[p] = 0.5f * ss;
  }
}

// ---------------- host side ----------------
template <int C, int O, int CN>
static void run_layer(const float* fin, void* const* w5, float* fout, float* Wc,
                      float* biasb, int* idx, float* Y, float* sqh,
                      unsigned* cval, ushort* Xhi, ushort* Xlo,
                      ushort* nxh, ushort* nxl, hipStream_t stream) {
  const float* W = (const float*)w5[0];
  const float* g = (const float*)w5[1];
  const float* bb = (const float*)w5[2];
  const float* mm = (const float*)w5[3];
  const float* vv = (const float*)w5[4];
  int N2 = 2 * O;
  prep_w<<<(2 * O * C + 255) / 256, 256, 0, stream>>>(W, g, bb, mm, vv, Wc,
                                                      biasb, O, C);
  if constexpr (C == 3) {
    cvt3_k<<<NBATCH * NTOT * 32 / 256, 256, 0, stream>>>(fin, Xhi, Xlo, sqh);
    knn_m<32><<<NBATCH * 32 * (JSPLIT / 2), 512, 0, stream>>>(Xhi, Xlo, sqh, cval);
    kref_w<3, 512><<<NBATCH * NTOT / 8, 256, 0, stream>>>(fin, cval, idx);
    dim3 gg(N2 / 64, NBATCH * NTOT / 64);
    gemm_k<<<gg, 256, 0, stream>>>(fin, Wc, biasb, Y, C, N2, O);
  } else {
    knn_m<C><<<NBATCH * 32 * (JSPLIT / 2), 512, 0, stream>>>(Xhi, Xlo, sqh, cval);
    kref_w<C, 512><<<NBATCH * NTOT / 8, 256, 0, stream>>>(fin, cval, idx);
    dim3 gg(N2 / 128, NBATCH * NTOT / 128);
    gemm128<<<gg, 256, 0, stream>>>(fin, Wc, biasb, Y, C, N2, O);
  }
  gmax_v<O, CN><<<NBATCH * NTOT / (256 / (O / 4)), 256, 0, stream>>>(
      Y, idx, fout, nxh, nxl, sqh);
}

extern "C" void kernel_launch(void* const* d_in, const int* in_sizes, int n_in,
                              void* d_out, int out_size, void* d_ws, size_t ws_size,
                              hipStream_t stream) {
  const float* x = (const float*)d_in[0];
  char* ws = (char*)d_ws;
  float* Wc = (float*)(ws + 0);            // 262144
  float* biasb = (float*)(ws + 262144);    // 1024
  int* idx = (int*)(ws + 263168);          // 1310720
  float* sqh = (float*)(ws + 1573888);     // 65536
  float* Y = (float*)(ws + 1639424);       // 33554432 -> ends 35193856
  float* x1 = (float*)(ws + 35193856);     // 4194304
  float* x2 = (float*)(ws + 39388160);     // 4194304
  float* x3 = (float*)(ws + 43582464);     // 8388608

  // cval (512 slots/point = 32MB) aliases Y (consumed by kref_w before gemm).
  unsigned* cval = (unsigned*)Y;
  // Xhi/Xlo live in each layer's OUTPUT buffer (dead until gmax_v writes it):
  ushort* X1h = (ushort*)x1;                          // layer1: C=32 pad -> 1MB+1MB
  ushort* X1l = X1h + (size_t)NBATCH * NTOT * 32;
  ushort* X2h = (ushort*)x2;                          // layer2: C=64 -> 2MB+2MB
  ushort* X2l = X2h + (size_t)NBATCH * NTOT * 64;
  ushort* X3h = (ushort*)x3;                          // layer3: C=64 -> 2MB+2MB
  ushort* X3l = X3h + (size_t)NBATCH * NTOT * 64;
  float* outf = (float*)d_out;
  ushort* X4h = (ushort*)outf;                        // layer4: C=128 -> 4MB+4MB
  ushort* X4l = X4h + (size_t)NBATCH * NTOT * 128;

  run_layer<3, 64, 64>(x, d_in + 1, x1, Wc, biasb, idx, Y, sqh, cval,
                       X1h, X1l, X2h, X2l, stream);
  run_layer<64, 64, 64>(x1, d_in + 6, x2, Wc, biasb, idx, Y, sqh, cval,
                        X2h, X2l, X3h, X3l, stream);
  run_layer<64, 128, 128>(x2, d_in + 11, x3, Wc, biasb, idx, Y, sqh, cval,
                          X3h, X3l, X4h, X4l, stream);
  run_layer<128, 256, 0>(x3, d_in + 16, outf, Wc, biasb, idx, Y, sqh, cval,
                         X4h, X4l, nullptr, nullptr, stream);
}